// Round 1
// baseline (2261.304 us; speedup 1.0000x reference)
//
#include <hip/hip_runtime.h>

// Stacked LSTM (4 layers, units 100/80/50/30) + dense head, fp32, B=T=512.
// Strategy: per-layer kernels; 256 blocks (2 batch rows each, 1 block/CU);
// weight columns k-split across threads and held in REGISTERS for all 512
// steps; concat(h,x) broadcast from LDS; partial z reduced via LDS; x(t+1)
// prefetched into regs during GEMV phase. All fp32 (no MFMA on purpose:
// threshold 4.37e-4 vs fp32 numpy ref over 512 recurrent steps).

#define T_SEQ 512
#define B_TOT 512

__device__ __forceinline__ float sigmoidf_(float x) {
    return 1.0f / (1.0f + __expf(-x));
}
__device__ __forceinline__ float tanh_fast(float x) {
    // tanh(x) = 1 - 2/(1 + e^{2x}); handles +-inf saturation correctly.
    float e = __expf(2.0f * x);
    return 1.0f - 2.0f / (1.0f + e);
}

// U: units, FI: input features. S: k-splits, JT: columns per thread.
// Thread tid<NT: p = tid%NP owns columns [JT*p, JT*p+JT), s = tid/NP owns
// k-range [s*KH, (s+1)*KH). Weights w[JT][KH] in registers (static unroll).
template<int U, int FI, int S, int JT, int BLOCK, bool SEQ, bool FINAL>
__global__ __launch_bounds__(BLOCK)
void lstm_layer(const float* __restrict__ X,    // [B][T][FI] layer input seq
                const float* __restrict__ W,    // [DIN][4U] row-major
                const float* __restrict__ Bv,   // [4U]
                float* __restrict__ Hout,       // [B][T][U] if SEQ
                const float* __restrict__ Wd,   // [U] dense weights (FINAL)
                const float* __restrict__ bd,   // [1]
                float* __restrict__ OUT)        // [B] (FINAL)
{
    constexpr int DIN  = U + FI;
    constexpr int DIN4 = ((DIN + 4*S - 1) / (4*S)) * (4*S);  // mult of 4S
    constexpr int KH   = DIN4 / S;                            // mult of 4
    constexpr int G    = 4 * U;
    constexpr int NP   = G / JT;
    constexpr int NT   = NP * S;

    __shared__ __align__(16) float in0[DIN4];   // concat(h, x) batch row 0
    __shared__ __align__(16) float in1[DIN4];   // concat(h, x) batch row 1
    __shared__ __align__(16) float zp[S * 2 * G];  // partial z [s][b][4U]

    const int tid = threadIdx.x;
    const int bb  = blockIdx.x * 2;   // batch base

    // ---- load weight tile into registers (once; reused 512 steps) ----
    const int p = tid % NP;
    const int s = tid / NP;
    float w[JT][KH];
    if (tid < NT) {
        #pragma unroll
        for (int c = 0; c < JT; ++c) {
            #pragma unroll
            for (int kk = 0; kk < KH; ++kk) {
                const int k = s * KH + kk;
                w[c][kk] = (k < DIN) ? W[(size_t)k * G + (JT * p + c)] : 0.0f;
            }
        }
    }

    // ---- cell-thread constants (threads [0, 2U)) ----
    const int cb = (tid < 2*U) ? (tid / U) : 0;
    const int cu = (tid < 2*U) ? (tid - cb*U) : 0;
    float gbf = 0, gbi = 0, gbg = 0, gbo = 0, creg = 0.0f;
    if (tid < 2*U) {
        gbf = Bv[cu]; gbi = Bv[cu + U]; gbg = Bv[cu + 2*U]; gbo = Bv[cu + 3*U];
    }
    float* myin = cb ? in1 : in0;

    // ---- x-stage mapping (threads [0, 2FI)) ----
    const int xb = (tid < 2*FI) ? (tid / FI) : 0;
    const int xk = (tid < 2*FI) ? (tid - xb*FI) : 0;
    const float* Xrow = X + (size_t)(bb + xb) * T_SEQ * FI + xk;
    float* xin = xb ? in1 : in0;

    // ---- init LDS: h=0, pad=0, stage x(0) ----
    for (int k = tid; k < DIN4; k += BLOCK) {
        if (k < U || k >= U + FI) { in0[k] = 0.0f; in1[k] = 0.0f; }
    }
    if (tid < 2*FI) xin[U + xk] = Xrow[0];
    __syncthreads();

    const float4* f40 = (const float4*)in0;
    const float4* f41 = (const float4*)in1;
    const int qbase = s * (KH / 4);

    for (int t = 0; t < T_SEQ; ++t) {
        // prefetch x(t+1) into regs; retires under the GEMV (T14 split)
        float xpre = 0.0f;
        const bool do_x = (tid < 2*FI) && (t + 1 < T_SEQ);
        if (do_x) xpre = Xrow[(size_t)(t + 1) * FI];

        // ---- phase 1: GEMV partials (weights in regs, h/x via LDS bcast) ----
        if (tid < NT) {
            float acc[JT][2];
            #pragma unroll
            for (int c = 0; c < JT; ++c) { acc[c][0] = 0.0f; acc[c][1] = 0.0f; }
            #pragma unroll
            for (int q = 0; q < KH/4; ++q) {
                const float4 av = f40[qbase + q];
                const float4 bv = f41[qbase + q];
                #pragma unroll
                for (int c = 0; c < JT; ++c) {
                    acc[c][0] += w[c][4*q+0] * av.x; acc[c][1] += w[c][4*q+0] * bv.x;
                    acc[c][0] += w[c][4*q+1] * av.y; acc[c][1] += w[c][4*q+1] * bv.y;
                    acc[c][0] += w[c][4*q+2] * av.z; acc[c][1] += w[c][4*q+2] * bv.z;
                    acc[c][0] += w[c][4*q+3] * av.w; acc[c][1] += w[c][4*q+3] * bv.w;
                }
            }
            float* z0 = &zp[(s*2 + 0) * G + JT * p];
            float* z1 = &zp[(s*2 + 1) * G + JT * p];
            #pragma unroll
            for (int c = 0; c < JT; ++c) { z0[c] = acc[c][0]; z1[c] = acc[c][1]; }
        }
        __syncthreads();

        // ---- phase 2: reduce + cell update; stage x(t+1) concurrently ----
        if (tid < 2*U) {
            float zf = gbf, zi = gbi, zg = gbg, zo = gbo;
            #pragma unroll
            for (int s2 = 0; s2 < S; ++s2) {
                const float* zr = &zp[(s2*2 + cb) * G];
                zf += zr[cu]; zi += zr[cu + U]; zg += zr[cu + 2*U]; zo += zr[cu + 3*U];
            }
            const float fg = sigmoidf_(zf);
            const float ig = sigmoidf_(zi);
            const float gg = tanh_fast(zg);
            const float og = sigmoidf_(zo);
            creg = fg * creg + ig * gg;
            const float hn = og * tanh_fast(creg);
            myin[cu] = hn;
            if constexpr (SEQ) {
                Hout[((size_t)(bb + cb) * T_SEQ + t) * U + cu] = hn;
            }
        }
        if (do_x) xin[U + xk] = xpre;
        __syncthreads();
    }

    if constexpr (FINAL) {
        if (tid < 2) {
            const float* hh = tid ? in1 : in0;
            float acc = bd[0];
            #pragma unroll
            for (int u2 = 0; u2 < U; ++u2) acc += hh[u2] * Wd[u2];
            OUT[bb + tid] = acc;
        }
    }
}

extern "C" void kernel_launch(void* const* d_in, const int* in_sizes, int n_in,
                              void* d_out, int out_size, void* d_ws, size_t ws_size,
                              hipStream_t stream)
{
    const float* x    = (const float*)d_in[0];
    const float* W0   = (const float*)d_in[1];
    const float* b0   = (const float*)d_in[2];
    const float* W1   = (const float*)d_in[3];
    const float* b1   = (const float*)d_in[4];
    const float* W2   = (const float*)d_in[5];
    const float* b2   = (const float*)d_in[6];
    const float* W3   = (const float*)d_in[7];
    const float* b3   = (const float*)d_in[8];
    const float* Wout = (const float*)d_in[9];
    const float* bout = (const float*)d_in[10];
    float* out = (float*)d_out;

    // Workspace: H0 [512*512*100], H1 [512*512*80]; H2 reuses H0's slot
    // (H0 is dead once layer-2 runs). Peak need = 188,743,680 B.
    float* H0 = (float*)d_ws;
    float* H1 = H0 + (size_t)B_TOT * T_SEQ * 100;
    float* H2 = (float*)d_ws;

    const dim3 grid(B_TOT / 2);

    hipLaunchKernelGGL((lstm_layer<100,  64, 4, 4, 448, true,  false>),
                       grid, dim3(448), 0, stream, x,  W0, b0, H0, nullptr, nullptr, nullptr);
    hipLaunchKernelGGL((lstm_layer< 80, 100, 4, 2, 640, true,  false>),
                       grid, dim3(640), 0, stream, H0, W1, b1, H1, nullptr, nullptr, nullptr);
    hipLaunchKernelGGL((lstm_layer< 50,  80, 4, 2, 448, true,  false>),
                       grid, dim3(448), 0, stream, H1, W2, b2, H2, nullptr, nullptr, nullptr);
    hipLaunchKernelGGL((lstm_layer< 30,  50, 4, 2, 256, false, true >),
                       grid, dim3(256), 0, stream, H2, W3, b3, nullptr, Wout, bout, out);
}

// Round 2
// 2258.996 us; speedup vs baseline: 1.0010x; 1.0010x over previous
//
#include <hip/hip_runtime.h>

// Stacked LSTM (4 layers, units 100/80/50/30) + dense head, fp32, B=T=512.
// Strategy: per-layer kernels; 256 blocks (2 batch rows each, 1 block/CU);
// weight columns k-split across threads and held in REGISTERS for all 512
// steps; concat(h,x) broadcast from LDS; partial z reduced via LDS; x(t+1)
// prefetched into regs during GEMV phase. All fp32 (no MFMA on purpose:
// threshold 4.37e-4 vs fp32 numpy ref over 512 recurrent steps).
//
// R1 fix: __launch_bounds__ second arg (min waves/EU) raises the VGPR cap so
// layer-0's 176-float weight slice actually stays in registers (R0 compiled
// to 128 VGPR -> reload/spill in the hot loop; VALUBusy 52%, 823us).

#define T_SEQ 512
#define B_TOT 512

__device__ __forceinline__ float sigmoidf_(float x) {
    return 1.0f / (1.0f + __expf(-x));
}
__device__ __forceinline__ float tanh_fast(float x) {
    // tanh(x) = 1 - 2/(1 + e^{2x}); handles +-inf saturation correctly.
    float e = __expf(2.0f * x);
    return 1.0f - 2.0f / (1.0f + e);
}

// U: units, FI: input features. S: k-splits, JT: columns per thread.
// Thread tid<NT: p = tid%NP owns columns [JT*p, JT*p+JT), s = tid/NP owns
// k-range [s*KH, (s+1)*KH). Weights w[JT][KH] in registers (static unroll).
// WEU: min waves per EU (second launch_bounds arg) -> VGPR cap = ~512/WEU.
template<int U, int FI, int S, int JT, int BLOCK, int WEU, bool SEQ, bool FINAL>
__global__ __launch_bounds__(BLOCK, WEU)
void lstm_layer(const float* __restrict__ X,    // [B][T][FI] layer input seq
                const float* __restrict__ W,    // [DIN][4U] row-major
                const float* __restrict__ Bv,   // [4U]
                float* __restrict__ Hout,       // [B][T][U] if SEQ
                const float* __restrict__ Wd,   // [U] dense weights (FINAL)
                const float* __restrict__ bd,   // [1]
                float* __restrict__ OUT)        // [B] (FINAL)
{
    constexpr int DIN  = U + FI;
    constexpr int DIN4 = ((DIN + 4*S - 1) / (4*S)) * (4*S);  // mult of 4S
    constexpr int KH   = DIN4 / S;                            // mult of 4
    constexpr int G    = 4 * U;
    constexpr int NP   = G / JT;
    constexpr int NT   = NP * S;

    __shared__ __align__(16) float in0[DIN4];   // concat(h, x) batch row 0
    __shared__ __align__(16) float in1[DIN4];   // concat(h, x) batch row 1
    __shared__ __align__(16) float zp[S * 2 * G];  // partial z [s][b][4U]

    const int tid = threadIdx.x;
    const int bb  = blockIdx.x * 2;   // batch base

    // ---- load weight tile into registers (once; reused 512 steps) ----
    const int p = tid % NP;
    const int s = tid / NP;
    float w[JT][KH];
    if (tid < NT) {
        #pragma unroll
        for (int c = 0; c < JT; ++c) {
            #pragma unroll
            for (int kk = 0; kk < KH; ++kk) {
                const int k = s * KH + kk;
                w[c][kk] = (k < DIN) ? W[(size_t)k * G + (JT * p + c)] : 0.0f;
            }
        }
    }

    // ---- cell-thread constants (threads [0, 2U)) ----
    const int cb = (tid < 2*U) ? (tid / U) : 0;
    const int cu = (tid < 2*U) ? (tid - cb*U) : 0;
    float gbf = 0, gbi = 0, gbg = 0, gbo = 0, creg = 0.0f;
    if (tid < 2*U) {
        gbf = Bv[cu]; gbi = Bv[cu + U]; gbg = Bv[cu + 2*U]; gbo = Bv[cu + 3*U];
    }
    float* myin = cb ? in1 : in0;

    // ---- x-stage mapping (threads [0, 2FI)) ----
    const int xb = (tid < 2*FI) ? (tid / FI) : 0;
    const int xk = (tid < 2*FI) ? (tid - xb*FI) : 0;
    const float* Xrow = X + (size_t)(bb + xb) * T_SEQ * FI + xk;
    float* xin = xb ? in1 : in0;

    // ---- init LDS: h=0, pad=0, stage x(0) ----
    for (int k = tid; k < DIN4; k += BLOCK) {
        if (k < U || k >= U + FI) { in0[k] = 0.0f; in1[k] = 0.0f; }
    }
    if (tid < 2*FI) xin[U + xk] = Xrow[0];
    __syncthreads();

    const float4* f40 = (const float4*)in0;
    const float4* f41 = (const float4*)in1;
    const int qbase = s * (KH / 4);

    for (int t = 0; t < T_SEQ; ++t) {
        // prefetch x(t+1) into regs; retires under the GEMV (T14 split)
        float xpre = 0.0f;
        const bool do_x = (tid < 2*FI) && (t + 1 < T_SEQ);
        if (do_x) xpre = Xrow[(size_t)(t + 1) * FI];

        // ---- phase 1: GEMV partials (weights in regs, h/x via LDS bcast) ----
        if (tid < NT) {
            float acc[JT][2];
            #pragma unroll
            for (int c = 0; c < JT; ++c) { acc[c][0] = 0.0f; acc[c][1] = 0.0f; }
            #pragma unroll
            for (int q = 0; q < KH/4; ++q) {
                const float4 av = f40[qbase + q];
                const float4 bv = f41[qbase + q];
                #pragma unroll
                for (int c = 0; c < JT; ++c) {
                    acc[c][0] += w[c][4*q+0] * av.x; acc[c][1] += w[c][4*q+0] * bv.x;
                    acc[c][0] += w[c][4*q+1] * av.y; acc[c][1] += w[c][4*q+1] * bv.y;
                    acc[c][0] += w[c][4*q+2] * av.z; acc[c][1] += w[c][4*q+2] * bv.z;
                    acc[c][0] += w[c][4*q+3] * av.w; acc[c][1] += w[c][4*q+3] * bv.w;
                }
            }
            float* z0 = &zp[(s*2 + 0) * G + JT * p];
            float* z1 = &zp[(s*2 + 1) * G + JT * p];
            #pragma unroll
            for (int c = 0; c < JT; ++c) { z0[c] = acc[c][0]; z1[c] = acc[c][1]; }
        }
        __syncthreads();

        // ---- phase 2: reduce + cell update; stage x(t+1) concurrently ----
        if (tid < 2*U) {
            float zf = gbf, zi = gbi, zg = gbg, zo = gbo;
            #pragma unroll
            for (int s2 = 0; s2 < S; ++s2) {
                const float* zr = &zp[(s2*2 + cb) * G];
                zf += zr[cu]; zi += zr[cu + U]; zg += zr[cu + 2*U]; zo += zr[cu + 3*U];
            }
            const float fg = sigmoidf_(zf);
            const float ig = sigmoidf_(zi);
            const float gg = tanh_fast(zg);
            const float og = sigmoidf_(zo);
            creg = fg * creg + ig * gg;
            const float hn = og * tanh_fast(creg);
            myin[cu] = hn;
            if constexpr (SEQ) {
                Hout[((size_t)(bb + cb) * T_SEQ + t) * U + cu] = hn;
            }
        }
        if (do_x) xin[U + xk] = xpre;
        __syncthreads();
    }

    if constexpr (FINAL) {
        if (tid < 2) {
            const float* hh = tid ? in1 : in0;
            float acc = bd[0];
            #pragma unroll
            for (int u2 = 0; u2 < U; ++u2) acc += hh[u2] * Wd[u2];
            OUT[bb + tid] = acc;
        }
    }
}

extern "C" void kernel_launch(void* const* d_in, const int* in_sizes, int n_in,
                              void* d_out, int out_size, void* d_ws, size_t ws_size,
                              hipStream_t stream)
{
    const float* x    = (const float*)d_in[0];
    const float* W0   = (const float*)d_in[1];
    const float* b0   = (const float*)d_in[2];
    const float* W1   = (const float*)d_in[3];
    const float* b1   = (const float*)d_in[4];
    const float* W2   = (const float*)d_in[5];
    const float* b2   = (const float*)d_in[6];
    const float* W3   = (const float*)d_in[7];
    const float* b3   = (const float*)d_in[8];
    const float* Wout = (const float*)d_in[9];
    const float* bout = (const float*)d_in[10];
    float* out = (float*)d_out;

    // Workspace: H0 [512*512*100], H1 [512*512*80]; H2 reuses H0's slot
    // (H0 is dead once layer-2 runs). Peak need = 188,743,680 B.
    float* H0 = (float*)d_ws;
    float* H1 = H0 + (size_t)B_TOT * T_SEQ * 100;
    float* H2 = (float*)d_ws;

    const dim3 grid(B_TOT / 2);

    // WEU (min waves/EU): L0 needs 256-VGPR cap for its 176-float weight
    // slice -> (448,2). L1's 96-float slice needs ~140 VGPR -> (640,3) caps
    // at ~168. L2/L3 fit under any cap.
    hipLaunchKernelGGL((lstm_layer<100,  64, 4, 4, 448, 2, true,  false>),
                       grid, dim3(448), 0, stream, x,  W0, b0, H0, nullptr, nullptr, nullptr);
    hipLaunchKernelGGL((lstm_layer< 80, 100, 4, 2, 640, 3, true,  false>),
                       grid, dim3(640), 0, stream, H0, W1, b1, H1, nullptr, nullptr, nullptr);
    hipLaunchKernelGGL((lstm_layer< 50,  80, 4, 2, 448, 2, true,  false>),
                       grid, dim3(448), 0, stream, H1, W2, b2, H2, nullptr, nullptr, nullptr);
    hipLaunchKernelGGL((lstm_layer< 30,  50, 4, 2, 256, 2, false, true >),
                       grid, dim3(256), 0, stream, H2, W3, b3, nullptr, Wout, bout, out);
}